// Round 6
// baseline (399.193 us; speedup 1.0000x reference)
//
#include <hip/hip_runtime.h>
#include <hip/hip_bf16.h>

#define B_ 32
#define S_ 2048
#define D_ 1024

// 128x128 tile, BK=64, 4 waves, 2 blocks/CU
#define BM 128
#define BN 128
#define BK 64
#define NKT (D_ / BK)   // 16 K-tiles

typedef __attribute__((ext_vector_type(8))) short bf16x8;
typedef __attribute__((ext_vector_type(4))) float f32x4;
typedef __attribute__((ext_vector_type(4))) float float4v;

#define AS1 __attribute__((address_space(1)))
#define AS3 __attribute__((address_space(3)))

// f32 -> bf16 round-to-nearest-even on raw bits
__device__ __forceinline__ short f2bf(float f) {
    union { float f; unsigned u; } uf;
    uf.f = f;
    unsigned u = uf.u;
    u += 0x7FFFu + ((u >> 16) & 1u);
    return (short)(u >> 16);
}

// ---------------- pre-convert W only: f32 -> bf16 --------------------------
__global__ __launch_bounds__(256) void cvt_bf16(const float4v* __restrict__ src,
                                                bf16x8* __restrict__ dst, int n8) {
    const int stride = gridDim.x * blockDim.x;
    for (int i = blockIdx.x * blockDim.x + threadIdx.x; i < n8; i += stride) {
        float4v a = src[2 * i], b = src[2 * i + 1];
        bf16x8 v;
#pragma unroll
        for (int j = 0; j < 4; ++j) {
            v[j]     = f2bf(a[j]);
            v[4 + j] = f2bf(b[j]);
        }
        dst[i] = v;
    }
}

// ============================================================================
// Fused GEMM: A read as f32 (reg-staged, converted in-kernel), B bf16 via
// global_load_lds. 4-phase/K-tile, double-buffered, counted vmcnt.
// LDS rows are half-permuted: half h holds global rows with bit5==h:
//   lds row l (in [h*64,(h+1)*64)) <-> global row (l_loc>>5)*64 + h*32 + (l_loc&31)
// Byte swizzle within a 128B row: stored byte = logical byte ^ ((l&7)<<4).
// ============================================================================

// ---- B half staging via global_load_lds (2 instr) ----
#define BGLLH(nb, h, kt) do {                                                  \
    _Pragma("unroll")                                                          \
    for (int _j = 0; _j < 2; ++_j) {                                           \
        const int _lr = (h) * 64 + _j * 32 + wid * 8 + lrow8;                  \
        const int _gr = _j * 64 + (h) * 32 + wid * 8 + lrow8;                  \
        const __hip_bfloat16* _g = bBase + (size_t)_gr * D_ + (kt) * BK + (scb >> 1); \
        __builtin_amdgcn_global_load_lds((const AS1 unsigned int*)_g,          \
            (AS3 unsigned int*)&Bs[nb][_lr * 64 + (lane & 7) * 8], 16, 0, 0);  \
    } } while (0)

// ---- A half load: 16 contiguous f32 into 4 named float4 regs ----
#define ALD(r0, r1, r2, r3, h, kt) do {                                        \
    const float* _s = aBase + (size_t)((al >> 5) * 64 + (h) * 32 + (al & 31)) * D_ \
                      + (kt) * BK + aCb;                                       \
    r0 = *(const float4v*)(_s);      r1 = *(const float4v*)(_s + 4);           \
    r2 = *(const float4v*)(_s + 8);  r3 = *(const float4v*)(_s + 12); } while (0)

// ---- A half publish: cvt 16 f32 -> 2 bf16x8, swizzled ds_write ----
#define AWRITE(nb, h, r0, r1, r2, r3) do {                                     \
    bf16x8 _lo, _hi;                                                           \
    _Pragma("unroll")                                                          \
    for (int _j = 0; _j < 4; ++_j) {                                           \
        _lo[_j]     = f2bf(r0[_j]);  _lo[4 + _j] = f2bf(r1[_j]);               \
        _hi[_j]     = f2bf(r2[_j]);  _hi[4 + _j] = f2bf(r3[_j]);               \
    }                                                                          \
    char* _d = (char*)&As[nb][0] + ((h) * 64 + al) * 128 + aa * 32;            \
    *(bf16x8*)(_d + (aswap ? 16 : 0)) = _lo;                                   \
    *(bf16x8*)(_d + (aswap ? 0 : 16)) = _hi; } while (0)

// ---- one quadrant: A-half mh x B-half bh, 8 MFMA ----
#define COMPUTE(cur, mh, bh) do {                                              \
    bf16x8 _af[2][2], _bv[2][2];                                               \
    _Pragma("unroll")                                                          \
    for (int _mi = 0; _mi < 2; ++_mi) {                                        \
        const int _l = (mh) * 64 + wm * 32 + _mi * 16 + fr;                    \
        _Pragma("unroll")                                                      \
        for (int _kk = 0; _kk < 2; ++_kk) {                                    \
            const int _b = _l * 128 + ((_kk * 64 + fg * 16) ^ ((_l & 7) << 4)); \
            _af[_mi][_kk] = *(const bf16x8*)((const char*)&As[cur][0] + _b);   \
        }                                                                      \
    }                                                                          \
    _Pragma("unroll")                                                          \
    for (int _ni = 0; _ni < 2; ++_ni) {                                        \
        const int _l = (bh) * 64 + wn * 32 + _ni * 16 + fr;                    \
        _Pragma("unroll")                                                      \
        for (int _kk = 0; _kk < 2; ++_kk) {                                    \
            const int _b = _l * 128 + ((_kk * 64 + fg * 16) ^ ((_l & 7) << 4)); \
            _bv[_ni][_kk] = *(const bf16x8*)((const char*)&Bs[cur][0] + _b);   \
        }                                                                      \
    }                                                                          \
    __builtin_amdgcn_s_setprio(1);                                             \
    _Pragma("unroll")                                                          \
    for (int _mi = 0; _mi < 2; ++_mi)                                          \
        _Pragma("unroll")                                                      \
        for (int _ni = 0; _ni < 2; ++_ni)                                      \
            _Pragma("unroll")                                                  \
            for (int _kk = 0; _kk < 2; ++_kk)                                  \
                acc[(mh) * 2 + _mi][(bh) * 2 + _ni] =                          \
                    __builtin_amdgcn_mfma_f32_16x16x32_bf16(                   \
                        _af[_mi][_kk], _bv[_ni][_kk],                          \
                        acc[(mh) * 2 + _mi][(bh) * 2 + _ni], 0, 0, 0);         \
    __builtin_amdgcn_s_setprio(0); } while (0)

#define VMW6()  asm volatile("s_waitcnt vmcnt(6)" ::: "memory")
#define LGK0()  asm volatile("s_waitcnt lgkmcnt(0)" ::: "memory")
#define SBAR()  asm volatile("s_barrier" ::: "memory")

// One K-tile: compute buf X, stage tile (via ktn) into buf Y.
// FIFO-verified waits: each vmcnt(6) completes exactly {the B-half gll issued
// 4 phases earlier + the A reg-loads issued 2 phases earlier}.
#define KITER(X, Y, ktn) do {                                                  \
    BGLLH(Y, 0, ktn);                                                          \
    SBAR();                 COMPUTE(X, 0, 0);                                  \
    ALD(an0, an1, an2, an3, 0, ktn);                                           \
    VMW6(); AWRITE(X, 1, ap0, ap1, ap2, ap3); LGK0();                          \
    SBAR();                 COMPUTE(X, 0, 1);                                  \
    BGLLH(Y, 1, ktn);                                                          \
    SBAR();                 COMPUTE(X, 1, 0);                                  \
    ALD(ap0, ap1, ap2, ap3, 1, ktn);                                           \
    VMW6(); AWRITE(Y, 0, an0, an1, an2, an3); LGK0();                          \
    SBAR();                 COMPUTE(X, 1, 1);                                  \
} while (0)

__global__ __launch_bounds__(256, 2) void fused_gemm_bf16(
    const float* __restrict__ aF,             // [B][S][D] f32 (midi, direct)
    const __hip_bfloat16* __restrict__ wBf,   // [3][D][D] bf16 (pre-converted)
    const int*   __restrict__ scale_id,
    const int*   __restrict__ mask,
    const float* __restrict__ bias,
    const float* __restrict__ scemb,
    const float* __restrict__ bremb,
    float*       __restrict__ out,
    float*       __restrict__ colws)
{
    __shared__ __align__(16) short As[2][BM * BK];   // 2 x 16 KB
    __shared__ __align__(16) short Bs[2][BM * BK];   // 2 x 16 KB  (total 64 KB)

    const int tid = threadIdx.x;
    const int lane = tid & 63;
    const int wid = tid >> 6;          // 0..3
    const int wm = wid >> 1, wn = wid & 1;   // 2x2 waves, 64x64 each

    // chunked XCD swizzle (NWG = 4096)
    const int NTI = D_ / BN;  // 8
    const int MTI = S_ / BM;  // 16
    const int NWG = B_ * MTI * NTI;
    const int CPX = NWG / 8;
    int lid = ((int)blockIdx.x % 8) * CPX + ((int)blockIdx.x / 8);
    int nt = lid % NTI;
    int mt = (lid / NTI) % MTI;
    int bb = lid / (NTI * MTI);

    const int sid = scale_id[bb];
    const float* aBase = aF + ((size_t)bb * S_ + (size_t)mt * BM) * D_;
    const __hip_bfloat16* bBase = wBf + ((size_t)sid * D_ + (size_t)nt * BN) * D_;

    // B staging lane geometry (pre-swizzled global source, linear LDS dest)
    const int lrow8 = lane >> 3;
    const int scb = ((lane & 7) * 16) ^ (lrow8 << 4);

    // A staging geometry: thread -> (local row al, stored chunk-pair aa)
    const int al = tid >> 2;             // 0..63
    const int aa = tid & 3;              // stored 32B pair index
    const int asb = (al & 7) << 4;       // row swizzle bits (4..6)
    const int aCb = (((aa * 32) ^ (asb & 0x60)) >> 1);  // logical f32 col base
    const int aswap = (asb >> 4) & 1;

    const int fr = lane & 15;
    const int fg = lane >> 4;

    f32x4 acc[4][4];
#pragma unroll
    for (int mi = 0; mi < 4; ++mi)
#pragma unroll
        for (int ni = 0; ni < 4; ++ni)
            acc[mi][ni] = (f32x4){0.f, 0.f, 0.f, 0.f};

    float4v an0, an1, an2, an3, ap0, ap1, ap2, ap3;

    // Prologue: tile 0 into buf 0; leaves FIFO = [B(0,h1):2, ap:4] (steady inv.)
    BGLLH(0, 0, 0);
    ALD(an0, an1, an2, an3, 0, 0);
    BGLLH(0, 1, 0);
    ALD(ap0, ap1, ap2, ap3, 1, 0);
    VMW6();                              // completes B(0,h0) + an
    AWRITE(0, 0, an0, an1, an2, an3);
    LGK0();

    for (int kt = 0; kt < NKT; kt += 2) {
        const int k1 = kt + 1;                           // <= 15
        const int k2 = (kt + 2 < NKT) ? kt + 2 : NKT - 1; // clamp (garbage restage)
        KITER(0, 1, k1);
        KITER(1, 0, k2);
    }

    asm volatile("s_waitcnt vmcnt(0) lgkmcnt(0)" ::: "memory");
    __syncthreads();   // drain tail garbage prefetch before LDS reuse

    // ---- epilogue phase 1: silu + scale_embed in-register, masked colsums ----
    // acc[mig][nig]: row = wm*64 + (mig>>1)*32 + (mig&1)*16 + fg*4 + r
    //               col = wn*64 + (nig>>1)*32 + (nig&1)*16 + fr
    const int colb = nt * BN;
    float bv[4], sv[4];
#pragma unroll
    for (int nig = 0; nig < 4; ++nig) {
        const int n = colb + wn * 64 + (nig >> 1) * 32 + (nig & 1) * 16 + fr;
        bv[nig] = bias[sid * D_ + n];
        sv[nig] = scemb[sid * D_ + n];
    }

    float colsum[4] = {0.f, 0.f, 0.f, 0.f};
#pragma unroll
    for (int mig = 0; mig < 4; ++mig) {
        const int mrow0 = mt * BM + wm * 64 + (mig >> 1) * 32 + (mig & 1) * 16 + fg * 4;
        float mk[4];
#pragma unroll
        for (int r = 0; r < 4; ++r)
            mk[r] = (mask[(size_t)bb * S_ + mrow0 + r] > 0) ? 1.f : 0.f;
#pragma unroll
        for (int nig = 0; nig < 4; ++nig)
#pragma unroll
            for (int r = 0; r < 4; ++r) {
                const float v = acc[mig][nig][r] + bv[nig];
                const float o = v / (1.f + __expf(-v)) + sv[nig];  // silu + scale_embed
                acc[mig][nig][r] = o;
                colsum[nig] += mk[r] * o;
            }
    }

#pragma unroll
    for (int nig = 0; nig < 4; ++nig) {
        float s = colsum[nig];
        s += __shfl_xor(s, 16);
        s += __shfl_xor(s, 32);
        if (fg == 0) {
            const int n = colb + wn * 64 + (nig >> 1) * 32 + (nig & 1) * 16 + fr;
            atomicAdd(&colws[(size_t)bb * D_ + n], s);
        }
    }

    // ---- epilogue phase 2: LDS bounce -> full-row contiguous float4 stores ----
    // ldsF[32][132] f32 = 16.9 KB in As. Per store instr: wave writes 2 rows x
    // 512B contiguous.
    float* ldsF = (float*)&As[0][0];
    const float4v b0 = *(const float4v*)&bremb[0 * D_ + colb + (lane & 31) * 4];
    const float4v b1 = *(const float4v*)&bremb[1 * D_ + colb + (lane & 31) * 4];
    const size_t MIDOFF = (size_t)B_ * S_ * D_;

#pragma unroll
    for (int mig = 0; mig < 4; ++mig) {
#pragma unroll
        for (int nig = 0; nig < 4; ++nig)
#pragma unroll
            for (int r = 0; r < 4; ++r)
                ldsF[(wm * 16 + fg * 4 + r) * 132 +
                     wn * 64 + (nig >> 1) * 32 + (nig & 1) * 16 + fr] =
                    acc[mig][nig][r];
        __syncthreads();

#pragma unroll
        for (int k = 0; k < 4; ++k) {
            const int lr = wid * 8 + k * 2 + (lane >> 5);   // 0..31
            const int grow = mt * BM + (lr >> 4) * 64 + (mig >> 1) * 32 +
                             (mig & 1) * 16 + (lr & 15);
            const size_t rowbase = ((size_t)bb * S_ + grow) * D_ + colb;
            float4v v = *(const float4v*)&ldsF[lr * 132 + (lane & 31) * 4];
            __builtin_nontemporal_store(v + b0, (float4v*)&out[rowbase + (lane & 31) * 4]);
            __builtin_nontemporal_store(v + b1, (float4v*)&out[MIDOFF + rowbase + (lane & 31) * 4]);
        }
        __syncthreads();
    }
}

// ---------------- fallback path (f32 reg-staging, 2-barrier) ---------------
__global__ __launch_bounds__(256, 2) void fused_gemm_f32(
    const float* __restrict__ midi,
    const int*   __restrict__ scale_id,
    const int*   __restrict__ mask,
    const float* __restrict__ W,
    const float* __restrict__ bias,
    const float* __restrict__ scemb,
    const float* __restrict__ bremb,
    float*       __restrict__ out,
    float*       __restrict__ ws)
{
    __shared__ __align__(16) short Asf[BM * BK];
    __shared__ __align__(16) short Bsf[BM * BK];

    const int tid = threadIdx.x;
    const int NTI = D_ / BN;
    const int MTI = S_ / BM;
    const int NWG = B_ * MTI * NTI;
    const int CPX = NWG / 8;
    int lid = ((int)blockIdx.x % 8) * CPX + ((int)blockIdx.x / 8);
    int nt = lid % NTI;
    int mt = (lid / NTI) % MTI;
    int bb = lid / (NTI * MTI);

    const int sid = scale_id[bb];
    const float* aBase = midi + ((size_t)bb * S_ + (size_t)mt * BM) * D_;
    const float* bBase = W + ((size_t)sid * D_ + (size_t)nt * BN) * D_;

    const int r0 = tid >> 3;
    const int kp = (tid & 7) * 8;

    float4v aL[4], aH[4], bL[4], bH[4];

    auto load_regs = [&](int kt) {
        const int kc = kt * BK + kp;
#pragma unroll
        for (int i = 0; i < 4; ++i) {
            const float* pa = aBase + (size_t)(r0 + 32 * i) * D_ + kc;
            aL[i] = *(const float4v*)pa;
            aH[i] = *(const float4v*)(pa + 4);
            const float* pb = bBase + (size_t)(r0 + 32 * i) * D_ + kc;
            bL[i] = *(const float4v*)pb;
            bH[i] = *(const float4v*)(pb + 4);
        }
    };

    auto write_lds = [&]() {
#pragma unroll
        for (int i = 0; i < 4; ++i) {
            const int row = r0 + 32 * i;
            const int off = (row * BK + kp) ^ ((row & 7) << 3);
            bf16x8 va, vb;
#pragma unroll
            for (int j = 0; j < 4; ++j) {
                va[j]     = f2bf(aL[i][j]);
                va[4 + j] = f2bf(aH[i][j]);
                vb[j]     = f2bf(bL[i][j]);
                vb[4 + j] = f2bf(bH[i][j]);
            }
            *(bf16x8*)&Asf[off] = va;
            *(bf16x8*)&Bsf[off] = vb;
        }
    };

    f32x4 acc[4][4];
#pragma unroll
    for (int mi = 0; mi < 4; ++mi)
#pragma unroll
        for (int ni = 0; ni < 4; ++ni)
            acc[mi][ni] = (f32x4){0.f, 0.f, 0.f, 0.f};

    const int lane = tid & 63;
    const int wid = tid >> 6;
    const int wm = wid >> 1, wn = wid & 1;
    const int fr = lane & 15;
    const int fg = lane >> 4;

    load_regs(0);
    write_lds();
    __syncthreads();

    for (int kt = 0; kt < NKT; ++kt) {
        if (kt + 1 < NKT) load_regs(kt + 1);
#pragma unroll
        for (int kk = 0; kk < 2; ++kk) {
            bf16x8 af[4], bfr[4];
#pragma unroll
            for (int mi = 0; mi < 4; ++mi) {
                const int row = wm * 64 + mi * 16 + fr;
                const int off = (row * BK + kk * 32 + fg * 8) ^ ((row & 7) << 3);
                af[mi] = *(const bf16x8*)&Asf[off];
            }
#pragma unroll
            for (int ni = 0; ni < 4; ++ni) {
                const int row = wn * 64 + ni * 16 + fr;
                const int off = (row * BK + kk * 32 + fg * 8) ^ ((row & 7) << 3);
                bfr[ni] = *(const bf16x8*)&Bsf[off];
            }
#pragma unroll
            for (int mi = 0; mi < 4; ++mi)
#pragma unroll
                for (int ni = 0; ni < 4; ++ni)
                    acc[mi][ni] = __builtin_amdgcn_mfma_f32_16x16x32_bf16(
                        af[mi], bfr[ni], acc[mi][ni], 0, 0, 0);
        }
        __syncthreads();
        if (kt + 1 < NKT) write_lds();
        __syncthreads();
    }

    const int ncolbase = nt * BN + wn * 64;
    float bv[4], sv[4], b0v[4], b1v[4];
#pragma unroll
    for (int ni = 0; ni < 4; ++ni) {
        const int n = ncolbase + ni * 16 + fr;
        bv[ni]  = bias[sid * D_ + n];
        sv[ni]  = scemb[sid * D_ + n];
        b0v[ni] = bremb[0 * D_ + n];
        b1v[ni] = bremb[1 * D_ + n];
    }

    const size_t MIDOFF = (size_t)B_ * S_ * D_;
    float colsum[4] = {0.f, 0.f, 0.f, 0.f};

#pragma unroll
    for (int mi = 0; mi < 4; ++mi) {
        const int mrow0 = mt * BM + wm * 64 + mi * 16 + fg * 4;
        float mk[4];
#pragma unroll
        for (int r = 0; r < 4; ++r)
            mk[r] = (mask[(size_t)bb * S_ + mrow0 + r] > 0) ? 1.f : 0.f;
#pragma unroll
        for (int ni = 0; ni < 4; ++ni) {
            const int n = ncolbase + ni * 16 + fr;
#pragma unroll
            for (int r = 0; r < 4; ++r) {
                const float v = acc[mi][ni][r] + bv[ni];
                const float o = v / (1.f + __expf(-v)) + sv[ni];
                const size_t idx = ((size_t)bb * S_ + (size_t)(mrow0 + r)) * D_ + n;
                __builtin_nontemporal_store(o + b0v[ni], &out[idx]);
                __builtin_nontemporal_store(o + b1v[ni], &out[MIDOFF + idx]);
                colsum[ni] += mk[r] * o;
            }
        }
    }

#pragma unroll
    for (int ni = 0; ni < 4; ++ni) {
        float s = colsum[ni];
        s += __shfl_xor(s, 16);
        s += __shfl_xor(s, 32);
        if (fg == 0)
            atomicAdd(&ws[(size_t)bb * D_ + (ncolbase + ni * 16 + fr)], s);
    }
}

__global__ void finalize(const int* __restrict__ mask,
                         const float* __restrict__ ws,
                         const float* __restrict__ bremb,
                         float* __restrict__ out)
{
    const int b = blockIdx.x;
    const int tid = threadIdx.x;

    int c = 0;
    for (int s = tid; s < S_; s += 256)
        c += (mask[(size_t)b * S_ + s] > 0) ? 1 : 0;
#pragma unroll
    for (int m = 1; m < 64; m <<= 1)
        c += __shfl_xor(c, m);

    __shared__ int part[4];
    if ((tid & 63) == 0) part[tid >> 6] = c;
    __syncthreads();
    const float denom = fmaxf((float)(part[0] + part[1] + part[2] + part[3]), 1e-6f);
    const float inv = 1.f / denom;

    const size_t LOWOFF = (size_t)2 * B_ * S_ * D_;
    for (int e = tid; e < D_; e += 256)
        out[LOWOFF + (size_t)b * D_ + e] = ws[(size_t)b * D_ + e] * inv + bremb[2 * D_ + e];
}

extern "C" void kernel_launch(void* const* d_in, const int* in_sizes, int n_in,
                              void* d_out, int out_size, void* d_ws, size_t ws_size,
                              hipStream_t stream) {
    const float* midi     = (const float*)d_in[0];
    const int*   scale_id = (const int*)d_in[1];
    const int*   mask     = (const int*)d_in[2];
    const float* W        = (const float*)d_in[3];
    const float* bias     = (const float*)d_in[4];
    const float* scemb    = (const float*)d_in[5];
    const float* bremb    = (const float*)d_in[6];
    float* out = (float*)d_out;
    float* colws = (float*)d_ws;

    const size_t COLWS_B = (size_t)B_ * D_ * sizeof(float);        // 128 KB
    const size_t WBF_B   = (size_t)3 * D_ * D_ * sizeof(short);    // 6 MB
    const size_t need    = COLWS_B + WBF_B;

    hipMemsetAsync(colws, 0, COLWS_B, stream);

    if (ws_size >= need) {
        __hip_bfloat16* wBf = (__hip_bfloat16*)((char*)d_ws + COLWS_B);
        cvt_bf16<<<dim3(512), dim3(256), 0, stream>>>(
            (const float4v*)W, (bf16x8*)wBf, (3 * D_ * D_) / 8);
        fused_gemm_bf16<<<dim3(B_ * (S_ / BM) * (D_ / BN)), dim3(256), 0, stream>>>(
            midi, wBf, scale_id, mask, bias, scemb, bremb, out, colws);
    } else {
        fused_gemm_f32<<<dim3(B_ * (S_ / BM) * (D_ / BN)), dim3(256), 0, stream>>>(
            midi, scale_id, mask, W, bias, scemb, bremb, out, colws);
    }

    finalize<<<dim3(B_), dim3(256), 0, stream>>>(mask, colws, bremb, out);
}